// Round 4
// baseline (359.672 us; speedup 1.0000x reference)
//
#include <hip/hip_runtime.h>
#include <math.h>

#define NNODES 50000
#define NEDGES 800000
#define COUT 64
#define TILE_E 64
#define NTILES (NEDGES / TILE_E)   // 12500, exact
#define RS 384                     // LDS row stride bytes (24 slots of 16B)
#define GRID 768                   // 256 CU x 3 blocks
#define KEY_NEG_INF 0x007FFFFFu    // fkey(-inf)

typedef short bf16x8 __attribute__((ext_vector_type(8)));
typedef float f32x4 __attribute__((ext_vector_type(4)));

// fp32 -> bf16 RTNE
__device__ __forceinline__ unsigned short f2bf(float x) {
    union { float f; unsigned u; } v; v.f = x;
    unsigned r = v.u + 0x7fffu + ((v.u >> 16) & 1u);
    return (unsigned short)(r >> 16);
}

// order-preserving float -> uint key (max over keys == max over floats)
__device__ __forceinline__ unsigned fkey(float v) {
    unsigned u = __float_as_uint(v);
    return u ^ ((unsigned)((int)u >> 31) | 0x80000000u);
}

// ---------------------------------------------------------------------------
// setup: zero histogram counters (ws is 0xAA-poisoned) + out <- key(-inf)
// ---------------------------------------------------------------------------
__global__ void setup_kernel(unsigned* __restrict__ out, unsigned* __restrict__ cnt) {
    int i = blockIdx.x * blockDim.x + threadIdx.x;
    int st = gridDim.x * blockDim.x;
    for (int j = i; j < NNODES; j += st) cnt[j] = 0u;
    for (int j = i; j < NNODES * COUT; j += st) out[j] = KEY_NEG_INF;
}

// histogram of dst
__global__ void hist_kernel(const int* __restrict__ ei, unsigned* __restrict__ cnt) {
    int i = blockIdx.x * blockDim.x + threadIdx.x;
    int st = gridDim.x * blockDim.x;
    for (int e = i; e < NEDGES; e += st) atomicAdd(&cnt[ei[NEDGES + e]], 1u);
}

// single-block exclusive scan of cnt[50000] -> cursor (scatter write heads)
__global__ __launch_bounds__(1024) void scan_kernel(const unsigned* __restrict__ cnt,
                                                    unsigned* __restrict__ cursor) {
    __shared__ unsigned ps[1024];
    const int t = threadIdx.x;
    const int CH = (NNODES + 1023) / 1024;        // 49
    const int base = t * CH;
    unsigned s = 0;
    for (int i = 0; i < CH; ++i) {
        int idx = base + i;
        if (idx < NNODES) s += cnt[idx];
    }
    ps[t] = s;
    __syncthreads();
    for (int off = 1; off < 1024; off <<= 1) {
        unsigned add = (t >= off) ? ps[t - off] : 0u;
        __syncthreads();
        ps[t] += add;
        __syncthreads();
    }
    unsigned run = ps[t] - s;                      // exclusive prefix
    for (int i = 0; i < CH; ++i) {
        int idx = base + i;
        if (idx < NNODES) { cursor[idx] = run; run += cnt[idx]; }
    }
}

// scatter edge ids into dst-sorted permutation
__global__ void scatter_kernel(const int* __restrict__ ei, unsigned* __restrict__ cursor,
                               int* __restrict__ perm) {
    int i = blockIdx.x * blockDim.x + threadIdx.x;
    int st = gridDim.x * blockDim.x;
    for (int e = i; e < NEDGES; e += st) {
        int d = ei[NEDGES + e];
        unsigned p = atomicAdd(&cursor[d], 1u);
        perm[p] = e;
    }
}

// unmap key -> float; -inf (no incoming edge) -> 0
__global__ void finalize_kernel(float* __restrict__ out, int n) {
    int i = blockIdx.x * blockDim.x + threadIdx.x;
    int stride = gridDim.x * blockDim.x;
    for (; i < n; i += stride) {
        unsigned k = ((unsigned*)out)[i];
        unsigned u = (k & 0x80000000u) ? (k ^ 0x80000000u) : ~k;
        out[i] = (u == 0xFF800000u) ? 0.0f : __uint_as_float(u);
    }
}

// ---------------------------------------------------------------------------
// MFMA edge kernel over dst-sorted edges. Per block-iter: 64 edges.
//  Augmented-K=160 msg tile (both types + bias row) @ W_aug -> 64x64 outputs.
//  Post-MFMA: keys -> LDS [64][65] u32, per-(col,16-row-quarter) serial
//  segmented max over sorted dsts, ONE atomic per run instead of per edge.
// ---------------------------------------------------------------------------
__global__ __launch_bounds__(256, 3) void edge_mfma_kernel(
    const float* __restrict__ feat, const float* __restrict__ pos,
    const float* __restrict__ W, const float* __restrict__ b,
    const int* __restrict__ ei, const int* __restrict__ ea,
    const int* __restrict__ perm, unsigned* __restrict__ out)
{
    __shared__ bf16x8 Amsg[TILE_E * (RS / 16)];   // 24576 B (also reused as K tile)
    __shared__ bf16x8 Wt[COUT * (RS / 16)];       // 24576 B
    __shared__ int dstv[TILE_E];

    const int tid = threadIdx.x;

    // ---- stage W_aug [col j][k] bf16, swizzled; once per block ----
    for (int idx = tid; idx < COUT * 160; idx += 256) {
        int k = idx >> 6;            // 0..159 (coalesced over j)
        int j = idx & 63;
        int t = (k >= 80);
        int kk = k - t * 80;
        float v = 0.0f;
        if (kk < 71)       v = W[(t * 71 + kk) * 64 + j];
        else if (kk == 71) v = b[t * 64 + j];
        int byte = j * RS + ((((k >> 3) ^ (j & 7)) << 4) | ((k & 7) * 2));
        *(unsigned short*)((char*)Wt + byte) = f2bf(v);
    }
    __syncthreads();

    const int e_local = tid >> 2, c = tid & 3;
    const int lane = tid & 63, w = tid >> 6;
    const int rg = w >> 1, cg = w & 1;
    const int la = lane & 15, lh = lane >> 4;
    const bf16x8 zero8 = {0, 0, 0, 0, 0, 0, 0, 0};

    for (int tile = blockIdx.x; tile < NTILES; tile += gridDim.x) {
        // ---------------- stage 64 sorted edges ----------------
        const int e = perm[tile * TILE_E + e_local];   // dst-sorted edge id
        const int src = ei[e];
        const int t = ea[e];
        const int ot = 1 - t;
        char* Ab = (char*)Amsg;
        const int rbase = e_local * RS;
        const int rx = e_local & 7;

        // 16 feat floats -> 2 bf16 slots
        const float4* fp = (const float4*)(feat + (long)src * 64 + c * 16);
        float4 f0 = fp[0], f1 = fp[1], f2 = fp[2], f3 = fp[3];
        union { bf16x8 v; unsigned short u[8]; } p0, p1;
        p0.u[0] = f2bf(f0.x); p0.u[1] = f2bf(f0.y); p0.u[2] = f2bf(f0.z); p0.u[3] = f2bf(f0.w);
        p0.u[4] = f2bf(f1.x); p0.u[5] = f2bf(f1.y); p0.u[6] = f2bf(f1.z); p0.u[7] = f2bf(f1.w);
        p1.u[0] = f2bf(f2.x); p1.u[1] = f2bf(f2.y); p1.u[2] = f2bf(f2.z); p1.u[3] = f2bf(f2.w);
        p1.u[4] = f2bf(f3.x); p1.u[5] = f2bf(f3.y); p1.u[6] = f2bf(f3.z); p1.u[7] = f2bf(f3.w);
        int s0 = t * 10 + c * 2;
        *(bf16x8*)(Ab + rbase + ((s0 ^ rx) << 4))       = p0.v;
        *(bf16x8*)(Ab + rbase + (((s0 + 1) ^ rx) << 4)) = p1.v;
        int z0 = ot * 10 + c * 2;
        *(bf16x8*)(Ab + rbase + ((z0 ^ rx) << 4))       = zero8;
        *(bf16x8*)(Ab + rbase + (((z0 + 1) ^ rx) << 4)) = zero8;

        if (c == 0) {
            int dst = ei[NEDGES + e];
            float ps0 = pos[src * 3], ps1 = pos[src * 3 + 1], ps2 = pos[src * 3 + 2];
            float d0 = pos[dst * 3] - ps0, d1 = pos[dst * 3 + 1] - ps1, d2 = pos[dst * 3 + 2] - ps2;
            float dist = sqrtf(d0 * d0 + d1 * d1 + d2 * d2);
            union { bf16x8 v; unsigned short u[8]; } pt;
            pt.u[0] = f2bf(ps0); pt.u[1] = f2bf(ps1); pt.u[2] = f2bf(ps2);
            pt.u[3] = f2bf(d0);  pt.u[4] = f2bf(d1);  pt.u[5] = f2bf(d2);
            pt.u[6] = f2bf(dist); pt.u[7] = f2bf(1.0f);
            *(bf16x8*)(Ab + rbase + (((t * 10 + 8) ^ rx) << 4)) = pt.v;
        } else if (c == 1) {
            *(bf16x8*)(Ab + rbase + (((ot * 10 + 8) ^ rx) << 4)) = zero8;
        } else if (c == 2) {
            *(bf16x8*)(Ab + rbase + (((ot * 10 + 9) ^ rx) << 4)) = zero8;
        } else {
            *(bf16x8*)(Ab + rbase + (((t * 10 + 9) ^ rx) << 4)) = zero8;
            dstv[e_local] = ei[NEDGES + e];
        }
        __syncthreads();

        // ---------------- mfma: 32x32 tile per wave ----------------
        f32x4 acc00 = {0,0,0,0}, acc01 = {0,0,0,0}, acc10 = {0,0,0,0}, acc11 = {0,0,0,0};
        const char* Ac = (const char*)Amsg;
        const char* Wc = (const char*)Wt;
        const int r0 = rg * 32 + la, r1 = r0 + 16;
        const int c0 = cg * 32 + la, c1 = c0 + 16;
        const int sx = la & 7;
        #pragma unroll
        for (int ks = 0; ks < 5; ++ks) {
            int slot = ks * 4 + lh;
            int so = (slot ^ sx) << 4;
            bf16x8 a0 = *(const bf16x8*)(Ac + r0 * RS + so);
            bf16x8 a1 = *(const bf16x8*)(Ac + r1 * RS + so);
            bf16x8 b0 = *(const bf16x8*)(Wc + c0 * RS + so);
            bf16x8 b1 = *(const bf16x8*)(Wc + c1 * RS + so);
            acc00 = __builtin_amdgcn_mfma_f32_16x16x32_bf16(a0, b0, acc00, 0, 0, 0);
            acc01 = __builtin_amdgcn_mfma_f32_16x16x32_bf16(a0, b1, acc01, 0, 0, 0);
            acc10 = __builtin_amdgcn_mfma_f32_16x16x32_bf16(a1, b0, acc10, 0, 0, 0);
            acc11 = __builtin_amdgcn_mfma_f32_16x16x32_bf16(a1, b1, acc11, 0, 0, 0);
        }
        __syncthreads();               // all waves done reading Amsg

        // ---------------- keys -> LDS [64][65] ----------------
        unsigned* K = (unsigned*)Amsg;
        const int col0 = cg * 32 + la, col1 = col0 + 16;
        #pragma unroll
        for (int i = 0; i < 4; ++i) {
            int er0 = rg * 32 + lh * 4 + i;
            int er1 = er0 + 16;
            K[er0 * 65 + col0] = fkey(acc00[i]);
            K[er0 * 65 + col1] = fkey(acc01[i]);
            K[er1 * 65 + col0] = fkey(acc10[i]);
            K[er1 * 65 + col1] = fkey(acc11[i]);
        }
        __syncthreads();

        // ---- segmented max: thread (col, quarter) scans 16 sorted rows ----
        {
            const int colr = tid & 63;
            const int rbeg = (tid >> 6) * 16;
            unsigned cur = K[rbeg * 65 + colr];
            int curd = dstv[rbeg];
            #pragma unroll
            for (int r = rbeg + 1; r < rbeg + 16; ++r) {
                unsigned k = K[r * 65 + colr];
                int d = dstv[r];
                if (d != curd) {
                    atomicMax(out + (long)curd * COUT + colr, cur);
                    curd = d; cur = k;
                } else {
                    cur = (k > cur) ? k : cur;
                }
            }
            atomicMax(out + (long)curd * COUT + colr, cur);
        }
        __syncthreads();               // protect Amsg/dstv before next staging
    }
}

extern "C" void kernel_launch(void* const* d_in, const int* in_sizes, int n_in,
                              void* d_out, int out_size, void* d_ws, size_t ws_size,
                              hipStream_t stream) {
    const float* feat = (const float*)d_in[0];
    const float* pos  = (const float*)d_in[1];
    const float* W    = (const float*)d_in[2];
    const float* b    = (const float*)d_in[3];
    const int*   ei   = (const int*)d_in[4];
    const int*   ea   = (const int*)d_in[5];
    unsigned* out = (unsigned*)d_out;

    // ws layout: cnt[50k] | cursor[50k] | perm[800k]   (~3.6 MB)
    unsigned* cnt    = (unsigned*)d_ws;
    unsigned* cursor = cnt + NNODES;
    int*      perm   = (int*)(cursor + NNODES);

    setup_kernel<<<2048, 256, 0, stream>>>(out, cnt);
    hist_kernel<<<2048, 256, 0, stream>>>(ei, cnt);
    scan_kernel<<<1, 1024, 0, stream>>>(cnt, cursor);
    scatter_kernel<<<2048, 256, 0, stream>>>(ei, cursor, perm);
    edge_mfma_kernel<<<GRID, 256, 0, stream>>>(feat, pos, W, b, ei, ea, perm, out);
    finalize_kernel<<<2048, 256, 0, stream>>>((float*)out, NNODES * COUT);
}

// Round 5
// 240.188 us; speedup vs baseline: 1.4975x; 1.4975x over previous
//
#include <hip/hip_runtime.h>
#include <math.h>

#define NNODES 50000
#define NEDGES 800000
#define COUT 64
#define TILE_E 64
#define NTILES (NEDGES / TILE_E)   // 12500, exact
#define GRID 1024                  // 256 CU x 4 blocks
#define KEY_NEG_INF 0x007FFFFFu    // fkey(-inf)
#define NPB 196                    // ceil(50000/256) scan blocks

typedef short bf16x8 __attribute__((ext_vector_type(8)));
typedef float f32x4 __attribute__((ext_vector_type(4)));

// fp32 -> bf16 RTNE
__device__ __forceinline__ unsigned short f2bf(float x) {
    union { float f; unsigned u; } v; v.f = x;
    unsigned r = v.u + 0x7fffu + ((v.u >> 16) & 1u);
    return (unsigned short)(r >> 16);
}

// order-preserving float -> uint key (max over keys == max over floats)
__device__ __forceinline__ unsigned fkey(float v) {
    unsigned u = __float_as_uint(v);
    return u ^ ((unsigned)((int)u >> 31) | 0x80000000u);
}

// ---------------------------------------------------------------------------
// setup: zero histogram + out <- key(-inf)
// ---------------------------------------------------------------------------
__global__ void setup_kernel(unsigned* __restrict__ out, unsigned* __restrict__ cnt) {
    int i = blockIdx.x * blockDim.x + threadIdx.x;
    int st = gridDim.x * blockDim.x;
    for (int j = i; j < NNODES; j += st) cnt[j] = 0u;
    for (int j = i; j < NNODES * COUT; j += st) out[j] = KEY_NEG_INF;
}

__global__ void hist_kernel(const int* __restrict__ ei, unsigned* __restrict__ cnt) {
    int i = blockIdx.x * blockDim.x + threadIdx.x;
    int st = gridDim.x * blockDim.x;
    for (int e = i; e < NEDGES; e += st) atomicAdd(&cnt[ei[NEDGES + e]], 1u);
}

// block partial sums of cnt (coalesced)
__global__ __launch_bounds__(256) void partial_kernel(const unsigned* __restrict__ cnt,
                                                      unsigned* __restrict__ part) {
    __shared__ unsigned ws[4];
    const int t = threadIdx.x;
    const int i = blockIdx.x * 256 + t;
    unsigned v = (i < NNODES) ? cnt[i] : 0u;
    #pragma unroll
    for (int off = 32; off; off >>= 1) v += __shfl_down(v, off, 64);
    if ((t & 63) == 0) ws[t >> 6] = v;
    __syncthreads();
    if (t == 0) part[blockIdx.x] = ws[0] + ws[1] + ws[2] + ws[3];
}

// exclusive scan of part[196] (single small block)
__global__ __launch_bounds__(256) void scanpart_kernel(const unsigned* __restrict__ part,
                                                       unsigned* __restrict__ partx) {
    __shared__ unsigned wsum[4];
    const int t = threadIdx.x, lane = t & 63, wv = t >> 6;
    unsigned orig = (t < NPB) ? part[t] : 0u;
    unsigned v = orig;
    #pragma unroll
    for (int off = 1; off < 64; off <<= 1) {
        unsigned n = __shfl_up(v, off, 64);
        if (lane >= off) v += n;
    }
    if (lane == 63) wsum[wv] = v;
    __syncthreads();
    unsigned wo = 0;
    for (int k = 0; k < 4; ++k) if (k < wv) wo += wsum[k];
    if (t < NPB) partx[t] = wo + v - orig;
}

// cursor[i] = global exclusive prefix of cnt
__global__ __launch_bounds__(256) void cursor_kernel(const unsigned* __restrict__ cnt,
                                                     const unsigned* __restrict__ partx,
                                                     unsigned* __restrict__ cursor) {
    __shared__ unsigned sh[256];
    const int t = threadIdx.x;
    const int i = blockIdx.x * 256 + t;
    unsigned v = (i < NNODES) ? cnt[i] : 0u;
    sh[t] = v;
    __syncthreads();
    for (int off = 1; off < 256; off <<= 1) {
        unsigned add = (t >= off) ? sh[t - off] : 0u;
        __syncthreads();
        sh[t] += add;
        __syncthreads();
    }
    if (i < NNODES) cursor[i] = partx[blockIdx.x] + sh[t] - v;
}

// scatter packed records into dst-sorted order: {src | type<<20, dst}
__global__ void scatter_kernel(const int* __restrict__ ei, const int* __restrict__ ea,
                               unsigned* __restrict__ cursor, int2* __restrict__ rec) {
    int i = blockIdx.x * blockDim.x + threadIdx.x;
    int st = gridDim.x * blockDim.x;
    for (int e = i; e < NEDGES; e += st) {
        int d = ei[NEDGES + e];
        unsigned p = atomicAdd(&cursor[d], 1u);
        rec[p] = make_int2(ei[e] | (ea[e] << 20), d);
    }
}

// unmap key -> float; -inf (no incoming edge) -> 0
__global__ void finalize_kernel(float* __restrict__ out, int n) {
    int i = blockIdx.x * blockDim.x + threadIdx.x;
    int stride = gridDim.x * blockDim.x;
    for (; i < n; i += stride) {
        unsigned k = ((unsigned*)out)[i];
        unsigned u = (k & 0x80000000u) ? (k ^ 0x80000000u) : ~k;
        out[i] = (u == 0xFF800000u) ? 0.0f : __uint_as_float(u);
    }
}

// ---------------------------------------------------------------------------
// MFMA edge kernel over dst-sorted packed records.
//  A tile TRANSPOSED in LDS: Amsg[slot][row] (20 slots x 64 rows x 16B =
//  20480B, conflict-free for b128 reads AND staging writes, no padding).
//  W_aug held in registers per wave (wb0/wb1[5], 40 VGPR) -- staged once
//  through the Amsg region. Keys tile Kt[64][64] with 5-bit col-XOR swizzle.
//  2 barriers/tile: B1 after staging, B2 after K-write; segscan overlaps
//  next tile's staging (dstv double-buffered).
// ---------------------------------------------------------------------------
__global__ __launch_bounds__(256, 4) void edge_mfma_kernel(
    const float* __restrict__ feat, const float* __restrict__ pos,
    const float* __restrict__ W, const float* __restrict__ b,
    const int2* __restrict__ rec, unsigned* __restrict__ out)
{
    __shared__ bf16x8 Amsg[20 * 64];      // 20480 B, [slot][row]
    __shared__ unsigned Kt[64 * 64];      // 16384 B, col-XOR swizzled
    __shared__ int dstv[2][TILE_E];       // double-buffered

    const int tid = threadIdx.x;
    const int lane = tid & 63, w = tid >> 6;
    const int rg = w >> 1, cg = w & 1;
    const int la = lane & 15, lh = lane >> 4;
    const bf16x8 zero8 = {0, 0, 0, 0, 0, 0, 0, 0};

    // ---- stage W_aug (transposed, via Amsg region) -> register fragments ----
    {
        char* Wb = (char*)Amsg;
        for (int idx = tid; idx < COUT * 160; idx += 256) {
            int k = idx >> 6, j = idx & 63;       // coalesced over j
            int t = (k >= 80);
            int kk = k - t * 80;
            float v = 0.0f;
            if (kk < 71)       v = W[(t * 71 + kk) * 64 + j];
            else if (kk == 71) v = b[t * 64 + j];
            *(unsigned short*)(Wb + (((k >> 3) * 64 + j) << 4) + ((k & 7) << 1)) = f2bf(v);
        }
    }
    __syncthreads();
    bf16x8 wb0[5], wb1[5];
    #pragma unroll
    for (int ks = 0; ks < 5; ++ks) {
        wb0[ks] = Amsg[(ks * 4 + lh) * 64 + cg * 32 + la];
        wb1[ks] = Amsg[(ks * 4 + lh) * 64 + cg * 32 + la + 16];
    }
    __syncthreads();    // all waves hold W frags before tile staging overwrites

    const int e_local = tid >> 2, c = tid & 3;

    int it = 0;
    for (int tile = blockIdx.x; tile < NTILES; tile += GRID, ++it) {
        const int p = it & 1;
        // ---------------- stage 64 sorted edges (coalesced rec) ----------------
        const int2 r2 = rec[tile * TILE_E + e_local];
        const int src = r2.x & 0xFFFFF;
        const int t = r2.x >> 20;
        const int ot = 1 - t;

        const float4* fp = (const float4*)(feat + (long)src * 64 + c * 16);
        float4 f0 = fp[0], f1 = fp[1], f2 = fp[2], f3 = fp[3];
        union { bf16x8 v; unsigned short u[8]; } p0, p1;
        p0.u[0] = f2bf(f0.x); p0.u[1] = f2bf(f0.y); p0.u[2] = f2bf(f0.z); p0.u[3] = f2bf(f0.w);
        p0.u[4] = f2bf(f1.x); p0.u[5] = f2bf(f1.y); p0.u[6] = f2bf(f1.z); p0.u[7] = f2bf(f1.w);
        p1.u[0] = f2bf(f2.x); p1.u[1] = f2bf(f2.y); p1.u[2] = f2bf(f2.z); p1.u[3] = f2bf(f2.w);
        p1.u[4] = f2bf(f3.x); p1.u[5] = f2bf(f3.y); p1.u[6] = f2bf(f3.z); p1.u[7] = f2bf(f3.w);
        const int s0 = t * 10 + c * 2, z0 = ot * 10 + c * 2;
        Amsg[s0 * 64 + e_local] = p0.v;
        Amsg[(s0 + 1) * 64 + e_local] = p1.v;
        Amsg[z0 * 64 + e_local] = zero8;
        Amsg[(z0 + 1) * 64 + e_local] = zero8;

        if (c == 0) {
            int dst = r2.y;
            float ps0 = pos[src * 3], ps1 = pos[src * 3 + 1], ps2 = pos[src * 3 + 2];
            float d0 = pos[dst * 3] - ps0, d1 = pos[dst * 3 + 1] - ps1, d2 = pos[dst * 3 + 2] - ps2;
            float dist = sqrtf(d0 * d0 + d1 * d1 + d2 * d2);
            union { bf16x8 v; unsigned short u[8]; } pt;
            pt.u[0] = f2bf(ps0); pt.u[1] = f2bf(ps1); pt.u[2] = f2bf(ps2);
            pt.u[3] = f2bf(d0);  pt.u[4] = f2bf(d1);  pt.u[5] = f2bf(d2);
            pt.u[6] = f2bf(dist); pt.u[7] = f2bf(1.0f);
            Amsg[(t * 10 + 8) * 64 + e_local] = pt.v;
        } else if (c == 1) {
            Amsg[(ot * 10 + 8) * 64 + e_local] = zero8;
        } else if (c == 2) {
            Amsg[(ot * 10 + 9) * 64 + e_local] = zero8;
        } else {
            Amsg[(t * 10 + 9) * 64 + e_local] = zero8;
            dstv[p][e_local] = r2.y;
        }
        __syncthreads();                                   // B1: tile staged

        // ---------------- mfma: 32x32 tile per wave, W from regs ----------------
        f32x4 acc00 = {0,0,0,0}, acc01 = {0,0,0,0}, acc10 = {0,0,0,0}, acc11 = {0,0,0,0};
        #pragma unroll
        for (int ks = 0; ks < 5; ++ks) {
            bf16x8 a0 = Amsg[(ks * 4 + lh) * 64 + rg * 32 + la];
            bf16x8 a1 = Amsg[(ks * 4 + lh) * 64 + rg * 32 + la + 16];
            acc00 = __builtin_amdgcn_mfma_f32_16x16x32_bf16(a0, wb0[ks], acc00, 0, 0, 0);
            acc01 = __builtin_amdgcn_mfma_f32_16x16x32_bf16(a0, wb1[ks], acc01, 0, 0, 0);
            acc10 = __builtin_amdgcn_mfma_f32_16x16x32_bf16(a1, wb0[ks], acc10, 0, 0, 0);
            acc11 = __builtin_amdgcn_mfma_f32_16x16x32_bf16(a1, wb1[ks], acc11, 0, 0, 0);
        }

        // ---------------- keys -> Kt (separate region; no barrier needed) ------
        const int col0 = cg * 32 + la, col1 = col0 + 16;
        #pragma unroll
        for (int i = 0; i < 4; ++i) {
            int er0 = rg * 32 + lh * 4 + i;
            int er1 = er0 + 16;
            Kt[er0 * 64 + (col0 ^ (er0 & 31))] = fkey(acc00[i]);
            Kt[er0 * 64 + (col1 ^ (er0 & 31))] = fkey(acc01[i]);
            Kt[er1 * 64 + (col0 ^ (er1 & 31))] = fkey(acc10[i]);
            Kt[er1 * 64 + (col1 ^ (er1 & 31))] = fkey(acc11[i]);
        }
        __syncthreads();                                   // B2: keys visible

        // ---- segmented max: thread (col, 16-row quarter), sorted dsts ----
        {
            const int colr = tid & 63;
            const int rbeg = (tid >> 6) * 16;
            unsigned cur = Kt[rbeg * 64 + (colr ^ (rbeg & 31))];
            int curd = dstv[p][rbeg];
            #pragma unroll
            for (int r = rbeg + 1; r < rbeg + 16; ++r) {
                unsigned k = Kt[r * 64 + (colr ^ (r & 31))];
                int d = dstv[p][r];
                if (d != curd) {
                    atomicMax(out + (long)curd * COUT + colr, cur);
                    curd = d; cur = k;
                } else {
                    cur = (k > cur) ? k : cur;
                }
            }
            atomicMax(out + (long)curd * COUT + colr, cur);
        }
        // no end barrier: next staging touches Amsg (reads done pre-B2) and
        // dstv[p^1] (other buffer); Kt n+1 writes are gated by B1(n+1).
    }
}

extern "C" void kernel_launch(void* const* d_in, const int* in_sizes, int n_in,
                              void* d_out, int out_size, void* d_ws, size_t ws_size,
                              hipStream_t stream) {
    const float* feat = (const float*)d_in[0];
    const float* pos  = (const float*)d_in[1];
    const float* W    = (const float*)d_in[2];
    const float* b    = (const float*)d_in[3];
    const int*   ei   = (const int*)d_in[4];
    const int*   ea   = (const int*)d_in[5];
    unsigned* out = (unsigned*)d_out;

    // ws layout: rec[800k] int2 | cnt[50k] | cursor[50k] | part[196] | partx[196]
    int2*     rec    = (int2*)d_ws;
    unsigned* cnt    = (unsigned*)(rec + NEDGES);
    unsigned* cursor = cnt + NNODES;
    unsigned* part   = cursor + NNODES;
    unsigned* partx  = part + NPB;

    setup_kernel<<<2048, 256, 0, stream>>>(out, cnt);
    hist_kernel<<<2048, 256, 0, stream>>>(ei, cnt);
    partial_kernel<<<NPB, 256, 0, stream>>>(cnt, part);
    scanpart_kernel<<<1, 256, 0, stream>>>(part, partx);
    cursor_kernel<<<NPB, 256, 0, stream>>>(cnt, partx, cursor);
    scatter_kernel<<<2048, 256, 0, stream>>>(ei, ea, cursor, rec);
    edge_mfma_kernel<<<GRID, 256, 0, stream>>>(feat, pos, W, b, rec, out);
    finalize_kernel<<<2048, 256, 0, stream>>>((float*)out, NNODES * COUT);
}